// Round 8
// baseline (572.834 us; speedup 1.0000x reference)
//
#include <hip/hip_runtime.h>
#include <hip/hip_bf16.h>
#include <math.h>

#define NBH 128      // B*H
#define LQ  4096
#define SK  4096
#define DH  64
#define NS  45       // U
#define TOPSTRIDE 48
#define NCH 8        // key chunks per bh (per block)
#define CK  512      // keys per block-chunk; each of 4 waves owns 128 keys

typedef __attribute__((ext_vector_type(8))) short short8v;
typedef __attribute__((ext_vector_type(4))) short short4v;
typedef __attribute__((ext_vector_type(4))) float f32x4;

static __device__ __forceinline__ short f2b(float x) {
    union { __hip_bfloat16 h; short s; } u;
    u.h = __float2bfloat16(x);
    return u.s;
}
static __device__ __forceinline__ short8v cvt8(const float* p) {
    float4 a = *(const float4*)p, b = *(const float4*)(p + 4);
    short8v r;
    r[0]=f2b(a.x); r[1]=f2b(a.y); r[2]=f2b(a.z); r[3]=f2b(a.w);
    r[4]=f2b(b.x); r[5]=f2b(b.y); r[6]=f2b(b.z); r[7]=f2b(b.w);
    return r;
}
static __device__ __forceinline__ f32x4 mfma16(short4v a, short4v b, f32x4 c) {
#if __has_builtin(__builtin_amdgcn_mfma_f32_16x16x16bf16_1k)
    return __builtin_amdgcn_mfma_f32_16x16x16bf16_1k(a, b, c, 0, 0, 0);
#else
    asm volatile("v_mfma_f32_16x16x16_bf16 %0, %1, %2, %0" : "+v"(c) : "v"(a), "v"(b));
    return c;
#endif
}

// ---------------- Kernel 1 (NEW): scalar-operand M-score, zero LDS ----------------
// K_sample rows are block-uniform -> readfirstlane forces SGPR loads; the dot
// becomes v_fma(vgpr_q, sgpr_k, acc). 45 static accumulators per thread.
__global__ __launch_bounds__(256) void kernelM(const float* __restrict__ Q,
                                               const float* __restrict__ K,
                                               const int* __restrict__ sidx,
                                               float* __restrict__ M) {
    const int bh = blockIdx.x >> 4;            // 16 blocks per bh
    const int q  = ((blockIdx.x & 15) << 8) + threadIdx.x;
    const float* qp = Q + (((size_t)bh << 12) + q) * DH;
    const size_t kbh = (size_t)bh * SK;
    float dacc[NS];
#pragma unroll
    for (int k = 0; k < NS; k++) dacc[k] = 0.f;
    for (int jt = 0; jt < 4; jt++) {
        float4 q0 = *(const float4*)(qp + jt * 16);
        float4 q1 = *(const float4*)(qp + jt * 16 + 4);
        float4 q2 = *(const float4*)(qp + jt * 16 + 8);
        float4 q3 = *(const float4*)(qp + jt * 16 + 12);
#pragma unroll
        for (int k = 0; k < NS; k++) {
            int row = __builtin_amdgcn_readfirstlane(sidx[k]);
            const float* kp = K + (kbh + row) * DH + jt * 16;
            float d = dacc[k];
            d = fmaf(q0.x, kp[0],  d); d = fmaf(q0.y, kp[1],  d);
            d = fmaf(q0.z, kp[2],  d); d = fmaf(q0.w, kp[3],  d);
            d = fmaf(q1.x, kp[4],  d); d = fmaf(q1.y, kp[5],  d);
            d = fmaf(q1.z, kp[6],  d); d = fmaf(q1.w, kp[7],  d);
            d = fmaf(q2.x, kp[8],  d); d = fmaf(q2.y, kp[9],  d);
            d = fmaf(q2.z, kp[10], d); d = fmaf(q2.w, kp[11], d);
            d = fmaf(q3.x, kp[12], d); d = fmaf(q3.y, kp[13], d);
            d = fmaf(q3.z, kp[14], d); d = fmaf(q3.w, kp[15], d);
            dacc[k] = d;
        }
    }
    float vmax = -INFINITY, vsum = 0.f;
#pragma unroll
    for (int k = 0; k < NS; k++) { vmax = fmaxf(vmax, dacc[k]); vsum += dacc[k]; }
    M[((size_t)bh << 12) + q] = vmax - vsum * (1.0f / 4096.0f);
}

// ---------------- Kernel 2 (NEW): register-resident incremental top-45 ----------------
// Each thread owns 16 strided M values in registers + a persistent local argmax.
// Per iteration: wave shfl-reduce + 4-slot LDS combine (1 barrier, ping-pong);
// only the winner thread rescans its 16 slots. Tie-break: lower index.
__global__ __launch_bounds__(256) void kernelTopK(const float* __restrict__ M,
                                                  int* __restrict__ top) {
    __shared__ float wv[2][4];
    __shared__ int   wi[2][4];
    const int bh = blockIdx.x, tid = threadIdx.x;
    const int w = tid >> 6, l = tid & 63;
    float mv[16];
    float bv = -INFINITY; int bi = 0x7fffffff;
#pragma unroll
    for (int s = 0; s < 16; s++) {
        mv[s] = M[((size_t)bh << 12) + tid + (s << 8)];
        if (mv[s] > bv) { bv = mv[s]; bi = tid + (s << 8); }
    }
    for (int it = 0; it < NS; ++it) {
        float rv = bv; int ri = bi;
#pragma unroll
        for (int off = 1; off < 64; off <<= 1) {
            float ov = __shfl_xor(rv, off, 64);
            int   oi = __shfl_xor(ri, off, 64);
            if (ov > rv || (ov == rv && oi < ri)) { rv = ov; ri = oi; }
        }
        const int buf = it & 1;
        if (l == 0) { wv[buf][w] = rv; wi[buf][w] = ri; }
        __syncthreads();
        float fv = wv[buf][0]; int fi = wi[buf][0];
#pragma unroll
        for (int ww = 1; ww < 4; ww++) {
            float ov = wv[buf][ww]; int oi = wi[buf][ww];
            if (ov > fv || (ov == fv && oi < fi)) { fv = ov; fi = oi; }
        }
        if (tid == 0) top[bh * TOPSTRIDE + it] = fi;
        if ((fi & 255) == tid) {
            const int slot = fi >> 8;
#pragma unroll
            for (int s = 0; s < 16; s++)
                if (s == slot) mv[s] = -INFINITY;
            bv = -INFINITY; bi = 0x7fffffff;
#pragma unroll
            for (int s = 0; s < 16; s++)
                if (mv[s] > bv) { bv = mv[s]; bi = tid + (s << 8); }
        }
    }
}

// ---------------- Kernel 3: MFMA attention (unchanged) ----------------
__global__ __launch_bounds__(256) void kernelAttn2(const float* __restrict__ Q,
                                                   const float* __restrict__ K,
                                                   const float* __restrict__ V,
                                                   const int* __restrict__ top,
                                                   float* __restrict__ pm,
                                                   float* __restrict__ pl,
                                                   float* __restrict__ pacc,
                                                   float* __restrict__ vsum) {
    __shared__ float lm[4][48];
    __shared__ float ll[4][48];
    __shared__ __attribute__((aligned(16))) float ob[48][68];

    const int bh = blockIdx.x >> 3, c = blockIdx.x & 7;
    const int tid = threadIdx.x, w = tid >> 6, l = tid & 63;
    const int b = l >> 4, n = l & 15;
    const int kwavebase = c * CK + w * 128;
    const size_t bhoff = ((size_t)bh << 12) * DH;

    const int* topb = top + bh * TOPSTRIDE;
    short8v qf[3][2];
#pragma unroll
    for (int qt = 0; qt < 3; qt++) {
        int q = qt * 16 + n;
        int row = topb[q < NS ? q : NS - 1];
        const float* qp = Q + bhoff + (size_t)row * DH;
#pragma unroll
        for (int t = 0; t < 2; t++) qf[qt][t] = cvt8(qp + 32 * t + 8 * b);
    }

    f32x4 o[3][4];
    float m_run[3], l_run[3], vacc[4];
#pragma unroll
    for (int qt = 0; qt < 3; qt++) {
        m_run[qt] = -INFINITY; l_run[qt] = 0.f;
#pragma unroll
        for (int dt = 0; dt < 4; dt++) { o[qt][dt][0]=0.f; o[qt][dt][1]=0.f; o[qt][dt][2]=0.f; o[qt][dt][3]=0.f; }
    }
#pragma unroll
    for (int dt = 0; dt < 4; dt++) vacc[dt] = 0.f;

    for (int s = 0; s < 8; ++s) {
        const float* kp = K + bhoff + (size_t)(kwavebase + s * 16 + n) * DH;
        short8v ka0 = cvt8(kp + 8 * b);
        short8v ka1 = cvt8(kp + 32 + 8 * b);
        const float* vp = V + bhoff + (size_t)(kwavebase + s * 16 + 4 * b) * DH;
        short4v vb[4];
#pragma unroll
        for (int dt = 0; dt < 4; dt++) {
            float v0 = vp[0 * DH + dt * 16 + n];
            float v1 = vp[1 * DH + dt * 16 + n];
            float v2 = vp[2 * DH + dt * 16 + n];
            float v3 = vp[3 * DH + dt * 16 + n];
            vacc[dt] += (v0 + v1) + (v2 + v3);
            short4v vv; vv[0]=f2b(v0); vv[1]=f2b(v1); vv[2]=f2b(v2); vv[3]=f2b(v3);
            vb[dt] = vv;
        }
        f32x4 st[3];
        float mnew[3];
        bool need = false;
#pragma unroll
        for (int qt = 0; qt < 3; qt++) {
            f32x4 acc0 = {0.f, 0.f, 0.f, 0.f};
            acc0 = __builtin_amdgcn_mfma_f32_16x16x32_bf16(ka0, qf[qt][0], acc0, 0, 0, 0);
            acc0 = __builtin_amdgcn_mfma_f32_16x16x32_bf16(ka1, qf[qt][1], acc0, 0, 0, 0);
            acc0 = acc0 * 0.125f;
            st[qt] = acc0;
            float tm = fmaxf(fmaxf(acc0[0], acc0[1]), fmaxf(acc0[2], acc0[3]));
            tm = fmaxf(tm, __shfl_xor(tm, 16, 64));
            tm = fmaxf(tm, __shfl_xor(tm, 32, 64));
            mnew[qt] = fmaxf(m_run[qt], tm);
            need = need || (mnew[qt] > m_run[qt]);
        }
        if (__any(need)) {
            float rl[3];
#pragma unroll
            for (int qt = 0; qt < 3; qt++) {
                rl[qt] = __expf(m_run[qt] - mnew[qt]);
                l_run[qt] *= rl[qt];
            }
#pragma unroll
            for (int qt = 0; qt < 3; qt++) {
#pragma unroll
                for (int rr = 0; rr < 4; rr++) {
                    float rs = __shfl(rl[qt], 20 * b + rr, 64);
#pragma unroll
                    for (int dt = 0; dt < 4; dt++) o[qt][dt][rr] *= rs;
                }
            }
        }
#pragma unroll
        for (int qt = 0; qt < 3; qt++) {
            float p0 = __expf(st[qt][0] - mnew[qt]);
            float p1 = __expf(st[qt][1] - mnew[qt]);
            float p2 = __expf(st[qt][2] - mnew[qt]);
            float p3 = __expf(st[qt][3] - mnew[qt]);
            float ps = (p0 + p1) + (p2 + p3);
            ps += __shfl_xor(ps, 16, 64);
            ps += __shfl_xor(ps, 32, 64);
            l_run[qt] += ps;
            m_run[qt] = mnew[qt];
            short4v pa; pa[0]=f2b(p0); pa[1]=f2b(p1); pa[2]=f2b(p2); pa[3]=f2b(p3);
#pragma unroll
            for (int dt = 0; dt < 4; dt++) o[qt][dt] = mfma16(pa, vb[dt], o[qt][dt]);
        }
    }

    if (b == 0) {
#pragma unroll
        for (int qt = 0; qt < 3; qt++) lm[w][qt * 16 + n] = m_run[qt];
    }
    __syncthreads();
    float wf[3];
    {
        float mblk[3], lw[3];
#pragma unroll
        for (int qt = 0; qt < 3; qt++) {
            int q = qt * 16 + n;
            mblk[qt] = fmaxf(fmaxf(lm[0][q], lm[1][q]), fmaxf(lm[2][q], lm[3][q]));
            wf[qt] = __expf(m_run[qt] - mblk[qt]);
            lw[qt] = l_run[qt] * wf[qt];
        }
        if (b == 0) {
#pragma unroll
            for (int qt = 0; qt < 3; qt++) ll[w][qt * 16 + n] = lw[qt];
        }
        if (w == 0 && b == 0) {
#pragma unroll
            for (int qt = 0; qt < 3; qt++) {
                int q = qt * 16 + n;
                if (q < NS) pm[(size_t)(bh * NCH + c) * TOPSTRIDE + q] = mblk[qt];
            }
        }
    }
    float wsh[3][4];
#pragma unroll
    for (int qt = 0; qt < 3; qt++)
#pragma unroll
        for (int rr = 0; rr < 4; rr++) wsh[qt][rr] = __shfl(wf[qt], 20 * b + rr, 64);

    for (int ww = 0; ww < 4; ++ww) {
        if (w == ww) {
#pragma unroll
            for (int qt = 0; qt < 3; qt++)
#pragma unroll
                for (int dt = 0; dt < 4; dt++)
#pragma unroll
                    for (int rr = 0; rr < 4; rr++) {
                        int q = qt * 16 + 4 * b + rr, d = dt * 16 + n;
                        float val = o[qt][dt][rr] * wsh[qt][rr];
                        if (ww == 0) ob[q][d] = val; else ob[q][d] += val;
                    }
        }
        __syncthreads();
    }
    if (w == 0 && b == 0) {
#pragma unroll
        for (int qt = 0; qt < 3; qt++) {
            int q = qt * 16 + n;
            if (q < NS)
                pl[(size_t)(bh * NCH + c) * TOPSTRIDE + q] =
                    ((ll[0][q] + ll[1][q]) + (ll[2][q] + ll[3][q]));
        }
    }
    for (int i = tid; i < NS * 16; i += 256) {
        int q = i >> 4, f4 = i & 15;
        float4 v = *(const float4*)&ob[q][f4 * 4];
        *(float4*)&pacc[((size_t)(bh * NCH + c) * TOPSTRIDE + q) * DH + f4 * 4] = v;
    }
#pragma unroll
    for (int dt = 0; dt < 4; dt++) {
        float t = vacc[dt];
        t += __shfl_xor(t, 16, 64);
        t += __shfl_xor(t, 32, 64);
        if (b == 0) atomicAdd(vsum + bh * DH + dt * 16 + n, t);
    }
}

// ---------------- Kernel 4: broadcast V_sum (unchanged) ----------------
__global__ __launch_bounds__(256) void kernelBroadcast(const float* __restrict__ vsum,
                                                       float4* __restrict__ out4) {
    size_t i = (size_t)blockIdx.x * 256 + threadIdx.x;
    int bh = (int)(i >> 16);
    int d4 = (int)(i & 15);
    out4[i] = *(const float4*)(vsum + bh * DH + d4 * 4);
}

// ---------------- Kernel 5: combine split-K partials (unchanged) ----------------
__global__ __launch_bounds__(256) void kernelCombine(const float* __restrict__ pm,
                                                     const float* __restrict__ pl,
                                                     const float* __restrict__ pacc,
                                                     const int* __restrict__ top,
                                                     float* __restrict__ out) {
    int g = (blockIdx.x << 2) | (threadIdx.x >> 6);
    int lane = threadIdx.x & 63;
    int bh = g / 45, u = g - bh * 45;
    float mc[NCH], lc[NCH];
    float mstar = -INFINITY;
#pragma unroll
    for (int c = 0; c < NCH; c++) {
        size_t pidx = ((size_t)bh * NCH + c) * TOPSTRIDE + u;
        mc[c] = pm[pidx]; lc[c] = pl[pidx];
        mstar = fmaxf(mstar, mc[c]);
    }
    float denom = 0.f, ctx = 0.f;
#pragma unroll
    for (int c = 0; c < NCH; c++) {
        size_t pidx = ((size_t)bh * NCH + c) * TOPSTRIDE + u;
        float wgt = __expf(mc[c] - mstar);
        denom += lc[c] * wgt;
        ctx += wgt * pacc[pidx * DH + lane];
    }
    int row = top[bh * TOPSTRIDE + u];
    out[(((size_t)bh << 12) + row) * DH + lane] = ctx / denom;
}

extern "C" void kernel_launch(void* const* d_in, const int* in_sizes, int n_in,
                              void* d_out, int out_size, void* d_ws, size_t ws_size,
                              hipStream_t stream) {
    const float* Q = (const float*)d_in[0];
    const float* K = (const float*)d_in[1];
    const float* V = (const float*)d_in[2];
    const int* sidx = (const int*)d_in[3];
    float* out = (float*)d_out;

    float* ws = (float*)d_ws;
    float* wsM    = ws;                                  // 524288
    int*   wsTop  = (int*)(ws + 524288);                 // 6144
    float* wsVsum = ws + 524288 + 6144;                  // 8192
    float* wsPm   = wsVsum + 8192;                       // 49152
    float* wsPl   = wsPm + 49152;                        // 49152
    float* wsPacc = wsPl + 49152;                        // 3145728

    hipMemsetAsync(wsVsum, 0, NBH * DH * sizeof(float), stream);
    kernelM<<<NBH * 16, 256, 0, stream>>>(Q, K, sidx, wsM);
    kernelTopK<<<NBH, 256, 0, stream>>>(wsM, wsTop);
    kernelAttn2<<<NBH * NCH, 256, 0, stream>>>(Q, K, V, wsTop, wsPm, wsPl, wsPacc, wsVsum);
    kernelBroadcast<<<32768, 256, 0, stream>>>(wsVsum, (float4*)out);
    kernelCombine<<<1440, 256, 0, stream>>>(wsPm, wsPl, wsPacc, wsTop, out);
}